// Round 1
// baseline (290.633 us; speedup 1.0000x reference)
//
#include <hip/hip_runtime.h>
#include <hip/hip_bf16.h>
#include <math.h>

// MultiHash R7: occupancy + VALU-debloat pass on the R6 MFMA kernel.
//  - LDS aliasing: preload ALL layer-1 A-fragments (both 32-sample halves,
//    +16 VGPR) right after encoding, so the feat region (sF) is dead before
//    the h1/h2 region (sA) is written. sA now ALIASES sF: LDS 19456->10240 B
//    -> 16 blocks/CU (was 8). __launch_bounds__(64,4) caps VGPR at 128 to
//    keep 4 waves/SIMD. Same-wave DS ops retire in order, so the
//    read-before-overwrite needs no barrier (single-wave block).
//  - Weight split prepass: W1/W2/W3 hi/lo bf16 split moved to a one-shot
//    prepass kernel into d_ws (28 KB). Kills ~28 splitW calls (~1.5k VALU
//    instrs) per wave; B-frags become 16B global loads (L1-resident).
//    W3 padded to 16 zero rows -> no divergent masked split on layer 3.
//  - Encoding math, fragment layouts, epilogues: unchanged from R6
//    (validated, absmax 1.49e-8 with 6x margin).

#define TBL_MASK 16383u
#define PRIME1   2654435761u

typedef __attribute__((ext_vector_type(8))) short short8;
typedef __attribute__((ext_vector_type(4))) float f32x4;
typedef __attribute__((ext_vector_type(4))) unsigned int uint4v;

struct ResArr { float r[16]; };

__device__ __forceinline__ unsigned short bf16rn(float f) {
    __hip_bfloat16 h = __float2bfloat16(f);   // RNE
    return __builtin_bit_cast(unsigned short, h);
}
__device__ __forceinline__ float bf16tof(unsigned short u) {
    unsigned int xx = ((unsigned int)u) << 16;
    return __builtin_bit_cast(float, xx);
}
__device__ __forceinline__ short8 ld8(const unsigned short* p) {
    return __builtin_bit_cast(short8, *(const uint4v*)p);
}

#define MFMA(a, b, c) __builtin_amdgcn_mfma_f32_16x16x32_bf16((a), (b), (c), 0, 0, 0)

// ---- workspace layout (ushort offsets), 16B-aligned blocks ----
#define W1H_OFF 0        // [64][32]
#define W1L_OFF 2048
#define W2H_OFF 4096     // [64][64]
#define W2L_OFF 8192
#define W3H_OFF 12288    // [16][64], rows 3..15 zero
#define W3L_OFF 13312
#define WS_USHORTS 14336 // 28672 B

__global__ __launch_bounds__(256) void split_weights(
    const float* __restrict__ W1, const float* __restrict__ W2,
    const float* __restrict__ W3, unsigned short* __restrict__ ws)
{
    const int t = blockIdx.x * blockDim.x + threadIdx.x;
    const int stride = gridDim.x * blockDim.x;
    for (int i = t; i < 2048; i += stride) {
        const float v = W1[i];
        const unsigned short hb = bf16rn(v);
        ws[W1H_OFF + i] = hb;
        ws[W1L_OFF + i] = bf16rn(v - bf16tof(hb));
    }
    for (int i = t; i < 4096; i += stride) {
        const float v = W2[i];
        const unsigned short hb = bf16rn(v);
        ws[W2H_OFF + i] = hb;
        ws[W2L_OFF + i] = bf16rn(v - bf16tof(hb));
    }
    for (int i = t; i < 1024; i += stride) {
        const float v = (i < 192) ? W3[i] : 0.0f;   // W3 is [3][64]; pad to 16 rows
        const unsigned short hb = bf16rn(v);
        ws[W3H_OFF + i] = hb;
        ws[W3L_OFF + i] = bf16rn(v - bf16tof(hb));
    }
}

__global__ __launch_bounds__(64, 4) void mh_mfma(
    const float* __restrict__ x,
    const float* __restrict__ tables,
    const unsigned short* __restrict__ wsw,
    const float* __restrict__ b1,
    const float* __restrict__ b2,
    const float* __restrict__ b3,
    float* __restrict__ out,
    ResArr res, int n)
{
    // One 10240 B region, two phases:
    //   phase F (encoding + layer-1 A-frag preload): sFH [64][40], sFL [64][40]
    //   phase A (h1/h2 staging):                     sAH [32][72], sAL [32][72]
    __shared__ __align__(16) unsigned short smem[5120];
    unsigned short* const sFH = smem;          // 2560 ushorts
    unsigned short* const sFL = smem + 2560;   // 2560 ushorts
    unsigned short* const sAH = smem;          // 2304 ushorts (aliases sFH)
    unsigned short* const sAL = smem + 2304;   // 2304 ushorts (aliases sFH/sFL)

    const int L  = threadIdx.x;
    const int ln = L & 15;
    const int q  = L >> 4;
    const long base = (long)blockIdx.x * 64;
    long s = base + L;
    if (s >= (long)n) s = (long)n - 1;   // clamp loads; stores predicated below

    const float2 xv = reinterpret_cast<const float2*>(x)[s];
    const float2* __restrict__ tbl2 = reinterpret_cast<const float2*>(tables);

    // ---- encoding: identical math to R1/R6 (validated) ----
    #pragma unroll 4
    for (int l = 0; l < 16; ++l) {
        const float r  = res.r[l];
        const float sx = xv.x * r;
        const float sy = xv.y * r;
        const float gx = floorf(sx);
        const float gy = floorf(sy);
        const unsigned ux = (unsigned)(int)gx;
        const unsigned uy = (unsigned)(int)gy;
        const unsigned hy0 = uy * PRIME1;
        const unsigned hy1 = hy0 + PRIME1;
        const unsigned i00 = ( ux       ^ hy0) & TBL_MASK;
        const unsigned i10 = ((ux + 1u) ^ hy0) & TBL_MASK;
        const unsigned i01 = ( ux       ^ hy1) & TBL_MASK;
        const unsigned i11 = ((ux + 1u) ^ hy1) & TBL_MASK;
        const float2* tl = tbl2 + (l << 14);
        const float2 t00 = tl[i00];
        const float2 t10 = tl[i10];
        const float2 t01 = tl[i01];
        const float2 t11 = tl[i11];
        const float wx0 = 1.0f - fabsf(sx - gx);
        const float wx1 = 1.0f - fabsf(sx - (gx + 1.0f));
        const float wy0 = 1.0f - fabsf(sy - gy);
        const float wy1 = 1.0f - fabsf(sy - (gy + 1.0f));
        const float w00 = wx0 * wy0;
        const float w10 = wx1 * wy0;
        const float w01 = wx0 * wy1;
        const float w11 = wx1 * wy1;
        const float f0 = fmaf(w00, t00.x, fmaf(w10, t10.x, fmaf(w01, t01.x, w11 * t11.x)));
        const float f1 = fmaf(w00, t00.y, fmaf(w10, t10.y, fmaf(w01, t01.y, w11 * t11.y)));
        const unsigned short h0 = bf16rn(f0);
        const unsigned short h1e = bf16rn(f1);
        const unsigned short l0 = bf16rn(f0 - bf16tof(h0));
        const unsigned short l1 = bf16rn(f1 - bf16tof(h1e));
        *(unsigned int*)&sFH[L * 40 + 2 * l] = (unsigned)h0 | ((unsigned)h1e << 16);
        *(unsigned int*)&sFL[L * 40 + 2 * l] = (unsigned)l0 | ((unsigned)l1 << 16);
    }

    // ---- preload ALL layer-1 A-fragments (both halves) while sF is live ----
    // After this, sF is dead and the sA writes below may alias it.
    short8 a1h[2][2], a1l[2][2];
    #pragma unroll
    for (int mh = 0; mh < 2; ++mh)
        #pragma unroll
        for (int mt = 0; mt < 2; ++mt) {
            const int row = mh * 32 + mt * 16 + ln;
            a1h[mh][mt] = ld8(&sFH[row * 40 + q * 8]);
            a1l[mh][mt] = ld8(&sFL[row * 40 + q * 8]);
        }

    // biases (per-lane by output column)
    float b1v[4], b2v[4];
    #pragma unroll
    for (int nt = 0; nt < 4; ++nt) { b1v[nt] = b1[nt * 16 + ln]; b2v[nt] = b2[nt * 16 + ln]; }
    const float b3v = (ln < 3) ? b3[ln] : 0.0f;

    const f32x4 zero4 = {0.0f, 0.0f, 0.0f, 0.0f};

    for (int mh = 0; mh < 2; ++mh) {          // 32-sample halves
        // ---------------- layer 1 ----------------
        f32x4 acc1[2][4];
        #pragma unroll
        for (int mt = 0; mt < 2; ++mt)
            #pragma unroll
            for (int nt = 0; nt < 4; ++nt) acc1[mt][nt] = zero4;

        #pragma unroll
        for (int nt = 0; nt < 4; ++nt) {
            const short8 bh = ld8(&wsw[W1H_OFF + (nt * 16 + ln) * 32 + q * 8]);
            const short8 bl = ld8(&wsw[W1L_OFF + (nt * 16 + ln) * 32 + q * 8]);
            #pragma unroll
            for (int mt = 0; mt < 2; ++mt) {
                f32x4 a = acc1[mt][nt];
                a = MFMA(a1l[mh][mt], bh, a);
                a = MFMA(a1h[mh][mt], bl, a);
                a = MFMA(a1h[mh][mt], bh, a);
                acc1[mt][nt] = a;
            }
        }
        // epilogue: bias + relu + split -> sAH/sAL rows 0..31 (aliases sF;
        // safe: all layer-1 A-frags preloaded, same-wave DS ops are in-order)
        #pragma unroll
        for (int mt = 0; mt < 2; ++mt)
            #pragma unroll
            for (int nt = 0; nt < 4; ++nt) {
                const int col = nt * 16 + ln;
                #pragma unroll
                for (int r = 0; r < 4; ++r) {
                    float v = fmaxf(acc1[mt][nt][r] + b1v[nt], 0.0f);
                    const unsigned short hb = bf16rn(v);
                    const unsigned short lb = bf16rn(v - bf16tof(hb));
                    const int rl = mt * 16 + q * 4 + r;
                    sAH[rl * 72 + col] = hb;
                    sAL[rl * 72 + col] = lb;
                }
            }

        // ---------------- layer 2 ----------------
        short8 a2h[2][2], a2l[2][2];
        #pragma unroll
        for (int mt = 0; mt < 2; ++mt)
            #pragma unroll
            for (int ks = 0; ks < 2; ++ks) {
                const int row = mt * 16 + ln;
                a2h[mt][ks] = ld8(&sAH[row * 72 + ks * 32 + q * 8]);
                a2l[mt][ks] = ld8(&sAL[row * 72 + ks * 32 + q * 8]);
            }
        f32x4 acc2[2][4];
        #pragma unroll
        for (int mt = 0; mt < 2; ++mt)
            #pragma unroll
            for (int nt = 0; nt < 4; ++nt) acc2[mt][nt] = zero4;

        #pragma unroll
        for (int nt = 0; nt < 4; ++nt)
            #pragma unroll
            for (int ks = 0; ks < 2; ++ks) {
                const short8 bh = ld8(&wsw[W2H_OFF + (nt * 16 + ln) * 64 + ks * 32 + q * 8]);
                const short8 bl = ld8(&wsw[W2L_OFF + (nt * 16 + ln) * 64 + ks * 32 + q * 8]);
                #pragma unroll
                for (int mt = 0; mt < 2; ++mt) {
                    f32x4 a = acc2[mt][nt];
                    a = MFMA(a2l[mt][ks], bh, a);
                    a = MFMA(a2h[mt][ks], bl, a);
                    a = MFMA(a2h[mt][ks], bh, a);
                    acc2[mt][nt] = a;
                }
            }
        // epilogue: bias + relu + split -> overwrite sAH/sAL (same-wave DS
        // ops retire in order; A-frags above were already read)
        #pragma unroll
        for (int mt = 0; mt < 2; ++mt)
            #pragma unroll
            for (int nt = 0; nt < 4; ++nt) {
                const int col = nt * 16 + ln;
                #pragma unroll
                for (int r = 0; r < 4; ++r) {
                    float v = fmaxf(acc2[mt][nt][r] + b2v[nt], 0.0f);
                    const unsigned short hb = bf16rn(v);
                    const unsigned short lb = bf16rn(v - bf16tof(hb));
                    const int rl = mt * 16 + q * 4 + r;
                    sAH[rl * 72 + col] = hb;
                    sAL[rl * 72 + col] = lb;
                }
            }

        // ---------------- layer 3 ----------------
        short8 a3h[2][2], a3l[2][2];
        #pragma unroll
        for (int mt = 0; mt < 2; ++mt)
            #pragma unroll
            for (int ks = 0; ks < 2; ++ks) {
                const int row = mt * 16 + ln;
                a3h[mt][ks] = ld8(&sAH[row * 72 + ks * 32 + q * 8]);
                a3l[mt][ks] = ld8(&sAL[row * 72 + ks * 32 + q * 8]);
            }
        f32x4 acc3[2] = {zero4, zero4};
        #pragma unroll
        for (int ks = 0; ks < 2; ++ks) {
            // W3 pre-padded to 16 rows (3..15 zero) -> no divergent mask
            const short8 bh = ld8(&wsw[W3H_OFF + ln * 64 + ks * 32 + q * 8]);
            const short8 bl = ld8(&wsw[W3L_OFF + ln * 64 + ks * 32 + q * 8]);
            #pragma unroll
            for (int mt = 0; mt < 2; ++mt) {
                f32x4 a = acc3[mt];
                a = MFMA(a3l[mt][ks], bh, a);
                a = MFMA(a3h[mt][ks], bl, a);
                a = MFMA(a3h[mt][ks], bh, a);
                acc3[mt] = a;
            }
        }
        // store: C col = ln (channel, <3), rows = samples
        if (ln < 3) {
            #pragma unroll
            for (int mt = 0; mt < 2; ++mt)
                #pragma unroll
                for (int r = 0; r < 4; ++r) {
                    const long sg = base + mh * 32 + mt * 16 + q * 4 + r;
                    if (sg < (long)n) out[sg * 3 + ln] = acc3[mt][r] + b3v;
                }
        }
    }
}

extern "C" void kernel_launch(void* const* d_in, const int* in_sizes, int n_in,
                              void* d_out, int out_size, void* d_ws, size_t ws_size,
                              hipStream_t stream) {
    const float* x      = (const float*)d_in[0];
    const float* tables = (const float*)d_in[1];
    const float* W1     = (const float*)d_in[2];
    const float* b1v    = (const float*)d_in[3];
    const float* W2     = (const float*)d_in[4];
    const float* b2v    = (const float*)d_in[5];
    const float* W3     = (const float*)d_in[6];
    const float* b3v    = (const float*)d_in[7];
    float* out = (float*)d_out;
    unsigned short* wsu = (unsigned short*)d_ws;

    const int n = in_sizes[0] / 2;   // B

    // Replicate numpy's RES computation on the host (glibc libm, float64).
    ResArr ra;
    const double bb = exp((log(512.0) - log(16.0)) / 15.0);
    for (int k = 0; k < 16; ++k) ra.r[k] = (float)floor(16.0 * pow(bb, (double)k));

    // Prepass: hi/lo bf16 weight split into workspace (stream-ordered).
    hipLaunchKernelGGL(split_weights, dim3(8), dim3(256), 0, stream, W1, W2, W3, wsu);

    dim3 grid((n + 63) / 64), block(64);
    hipLaunchKernelGGL(mh_mfma, grid, block, 0, stream,
                       x, tables, wsu, b1v, b2v, b3v, out, ra, n);
}

// Round 2
// 277.536 us; speedup vs baseline: 1.0472x; 1.0472x over previous
//
#include <hip/hip_runtime.h>
#include <hip/hip_bf16.h>
#include <math.h>

// MultiHash R8: fix R7's register-spill regression.
// R7 post-mortem: __launch_bounds__(64,4) capped regs at 128; live set is
// ~145 (112 arch VGPR + 16 cross-half a1 preload + AGPR accumulators), so
// the compiler spilled ~15 dwords/lane to scratch -> WRITE_SIZE 12MB->78MB,
// dur 187->240us despite occupancy doubling.
// R8: __launch_bounds__(64,3) -> reg cap ~168, no spill, 3 waves/SIMD =
// 12 single-wave blocks/CU (LDS 10240 B would allow 16; VGPR binds).
// Everything else identical to R7:
//  - LDS aliasing: preload ALL layer-1 A-fragments (both 32-sample halves)
//    right after encoding so the feat region is dead before h1/h2 staging
//    overwrites it. LDS 19456 -> 10240 B.
//  - Weight split prepass into d_ws (28 KB): B-frags are plain 16B global
//    loads (L1-resident); no per-wave splitW VALU bloat; W3 zero-padded to
//    16 rows so layer 3 has no divergent masked split.
//  - Encoding math, fragment layouts, epilogues: R6-validated
//    (absmax 1.49e-8, threshold 8.9e-8).

#define TBL_MASK 16383u
#define PRIME1   2654435761u

typedef __attribute__((ext_vector_type(8))) short short8;
typedef __attribute__((ext_vector_type(4))) float f32x4;
typedef __attribute__((ext_vector_type(4))) unsigned int uint4v;

struct ResArr { float r[16]; };

__device__ __forceinline__ unsigned short bf16rn(float f) {
    __hip_bfloat16 h = __float2bfloat16(f);   // RNE
    return __builtin_bit_cast(unsigned short, h);
}
__device__ __forceinline__ float bf16tof(unsigned short u) {
    unsigned int xx = ((unsigned int)u) << 16;
    return __builtin_bit_cast(float, xx);
}
__device__ __forceinline__ short8 ld8(const unsigned short* p) {
    return __builtin_bit_cast(short8, *(const uint4v*)p);
}

#define MFMA(a, b, c) __builtin_amdgcn_mfma_f32_16x16x32_bf16((a), (b), (c), 0, 0, 0)

// ---- workspace layout (ushort offsets), 16B-aligned blocks ----
#define W1H_OFF 0        // [64][32]
#define W1L_OFF 2048
#define W2H_OFF 4096     // [64][64]
#define W2L_OFF 8192
#define W3H_OFF 12288    // [16][64], rows 3..15 zero
#define W3L_OFF 13312
#define WS_USHORTS 14336 // 28672 B

__global__ __launch_bounds__(256) void split_weights(
    const float* __restrict__ W1, const float* __restrict__ W2,
    const float* __restrict__ W3, unsigned short* __restrict__ ws)
{
    const int t = blockIdx.x * blockDim.x + threadIdx.x;
    const int stride = gridDim.x * blockDim.x;
    for (int i = t; i < 2048; i += stride) {
        const float v = W1[i];
        const unsigned short hb = bf16rn(v);
        ws[W1H_OFF + i] = hb;
        ws[W1L_OFF + i] = bf16rn(v - bf16tof(hb));
    }
    for (int i = t; i < 4096; i += stride) {
        const float v = W2[i];
        const unsigned short hb = bf16rn(v);
        ws[W2H_OFF + i] = hb;
        ws[W2L_OFF + i] = bf16rn(v - bf16tof(hb));
    }
    for (int i = t; i < 1024; i += stride) {
        const float v = (i < 192) ? W3[i] : 0.0f;   // W3 is [3][64]; pad to 16 rows
        const unsigned short hb = bf16rn(v);
        ws[W3H_OFF + i] = hb;
        ws[W3L_OFF + i] = bf16rn(v - bf16tof(hb));
    }
}

__global__ __launch_bounds__(64, 3) void mh_mfma(
    const float* __restrict__ x,
    const float* __restrict__ tables,
    const unsigned short* __restrict__ wsw,
    const float* __restrict__ b1,
    const float* __restrict__ b2,
    const float* __restrict__ b3,
    float* __restrict__ out,
    ResArr res, int n)
{
    // One 10240 B region, two phases:
    //   phase F (encoding + layer-1 A-frag preload): sFH [64][40], sFL [64][40]
    //   phase A (h1/h2 staging):                     sAH [32][72], sAL [32][72]
    __shared__ __align__(16) unsigned short smem[5120];
    unsigned short* const sFH = smem;          // 2560 ushorts
    unsigned short* const sFL = smem + 2560;   // 2560 ushorts
    unsigned short* const sAH = smem;          // 2304 ushorts (aliases sFH)
    unsigned short* const sAL = smem + 2304;   // 2304 ushorts (aliases sFH/sFL)

    const int L  = threadIdx.x;
    const int ln = L & 15;
    const int q  = L >> 4;
    const long base = (long)blockIdx.x * 64;
    long s = base + L;
    if (s >= (long)n) s = (long)n - 1;   // clamp loads; stores predicated below

    const float2 xv = reinterpret_cast<const float2*>(x)[s];
    const float2* __restrict__ tbl2 = reinterpret_cast<const float2*>(tables);

    // ---- encoding: identical math to R1/R6 (validated) ----
    #pragma unroll 4
    for (int l = 0; l < 16; ++l) {
        const float r  = res.r[l];
        const float sx = xv.x * r;
        const float sy = xv.y * r;
        const float gx = floorf(sx);
        const float gy = floorf(sy);
        const unsigned ux = (unsigned)(int)gx;
        const unsigned uy = (unsigned)(int)gy;
        const unsigned hy0 = uy * PRIME1;
        const unsigned hy1 = hy0 + PRIME1;
        const unsigned i00 = ( ux       ^ hy0) & TBL_MASK;
        const unsigned i10 = ((ux + 1u) ^ hy0) & TBL_MASK;
        const unsigned i01 = ( ux       ^ hy1) & TBL_MASK;
        const unsigned i11 = ((ux + 1u) ^ hy1) & TBL_MASK;
        const float2* tl = tbl2 + (l << 14);
        const float2 t00 = tl[i00];
        const float2 t10 = tl[i10];
        const float2 t01 = tl[i01];
        const float2 t11 = tl[i11];
        const float wx0 = 1.0f - fabsf(sx - gx);
        const float wx1 = 1.0f - fabsf(sx - (gx + 1.0f));
        const float wy0 = 1.0f - fabsf(sy - gy);
        const float wy1 = 1.0f - fabsf(sy - (gy + 1.0f));
        const float w00 = wx0 * wy0;
        const float w10 = wx1 * wy0;
        const float w01 = wx0 * wy1;
        const float w11 = wx1 * wy1;
        const float f0 = fmaf(w00, t00.x, fmaf(w10, t10.x, fmaf(w01, t01.x, w11 * t11.x)));
        const float f1 = fmaf(w00, t00.y, fmaf(w10, t10.y, fmaf(w01, t01.y, w11 * t11.y)));
        const unsigned short h0 = bf16rn(f0);
        const unsigned short h1e = bf16rn(f1);
        const unsigned short l0 = bf16rn(f0 - bf16tof(h0));
        const unsigned short l1 = bf16rn(f1 - bf16tof(h1e));
        *(unsigned int*)&sFH[L * 40 + 2 * l] = (unsigned)h0 | ((unsigned)h1e << 16);
        *(unsigned int*)&sFL[L * 40 + 2 * l] = (unsigned)l0 | ((unsigned)l1 << 16);
    }

    // ---- preload ALL layer-1 A-fragments (both halves) while sF is live ----
    // After this, sF is dead and the sA writes below may alias it.
    short8 a1h[2][2], a1l[2][2];
    #pragma unroll
    for (int mh = 0; mh < 2; ++mh)
        #pragma unroll
        for (int mt = 0; mt < 2; ++mt) {
            const int row = mh * 32 + mt * 16 + ln;
            a1h[mh][mt] = ld8(&sFH[row * 40 + q * 8]);
            a1l[mh][mt] = ld8(&sFL[row * 40 + q * 8]);
        }

    // biases (per-lane by output column)
    float b1v[4], b2v[4];
    #pragma unroll
    for (int nt = 0; nt < 4; ++nt) { b1v[nt] = b1[nt * 16 + ln]; b2v[nt] = b2[nt * 16 + ln]; }
    const float b3v = (ln < 3) ? b3[ln] : 0.0f;

    const f32x4 zero4 = {0.0f, 0.0f, 0.0f, 0.0f};

    for (int mh = 0; mh < 2; ++mh) {          // 32-sample halves
        // ---------------- layer 1 ----------------
        f32x4 acc1[2][4];
        #pragma unroll
        for (int mt = 0; mt < 2; ++mt)
            #pragma unroll
            for (int nt = 0; nt < 4; ++nt) acc1[mt][nt] = zero4;

        #pragma unroll
        for (int nt = 0; nt < 4; ++nt) {
            const short8 bh = ld8(&wsw[W1H_OFF + (nt * 16 + ln) * 32 + q * 8]);
            const short8 bl = ld8(&wsw[W1L_OFF + (nt * 16 + ln) * 32 + q * 8]);
            #pragma unroll
            for (int mt = 0; mt < 2; ++mt) {
                f32x4 a = acc1[mt][nt];
                a = MFMA(a1l[mh][mt], bh, a);
                a = MFMA(a1h[mh][mt], bl, a);
                a = MFMA(a1h[mh][mt], bh, a);
                acc1[mt][nt] = a;
            }
        }
        // epilogue: bias + relu + split -> sAH/sAL rows 0..31 (aliases sF;
        // safe: all layer-1 A-frags preloaded, same-wave DS ops are in-order)
        #pragma unroll
        for (int mt = 0; mt < 2; ++mt)
            #pragma unroll
            for (int nt = 0; nt < 4; ++nt) {
                const int col = nt * 16 + ln;
                #pragma unroll
                for (int r = 0; r < 4; ++r) {
                    float v = fmaxf(acc1[mt][nt][r] + b1v[nt], 0.0f);
                    const unsigned short hb = bf16rn(v);
                    const unsigned short lb = bf16rn(v - bf16tof(hb));
                    const int rl = mt * 16 + q * 4 + r;
                    sAH[rl * 72 + col] = hb;
                    sAL[rl * 72 + col] = lb;
                }
            }

        // ---------------- layer 2 ----------------
        short8 a2h[2][2], a2l[2][2];
        #pragma unroll
        for (int mt = 0; mt < 2; ++mt)
            #pragma unroll
            for (int ks = 0; ks < 2; ++ks) {
                const int row = mt * 16 + ln;
                a2h[mt][ks] = ld8(&sAH[row * 72 + ks * 32 + q * 8]);
                a2l[mt][ks] = ld8(&sAL[row * 72 + ks * 32 + q * 8]);
            }
        f32x4 acc2[2][4];
        #pragma unroll
        for (int mt = 0; mt < 2; ++mt)
            #pragma unroll
            for (int nt = 0; nt < 4; ++nt) acc2[mt][nt] = zero4;

        #pragma unroll
        for (int nt = 0; nt < 4; ++nt)
            #pragma unroll
            for (int ks = 0; ks < 2; ++ks) {
                const short8 bh = ld8(&wsw[W2H_OFF + (nt * 16 + ln) * 64 + ks * 32 + q * 8]);
                const short8 bl = ld8(&wsw[W2L_OFF + (nt * 16 + ln) * 64 + ks * 32 + q * 8]);
                #pragma unroll
                for (int mt = 0; mt < 2; ++mt) {
                    f32x4 a = acc2[mt][nt];
                    a = MFMA(a2l[mt][ks], bh, a);
                    a = MFMA(a2h[mt][ks], bl, a);
                    a = MFMA(a2h[mt][ks], bh, a);
                    acc2[mt][nt] = a;
                }
            }
        // epilogue: bias + relu + split -> overwrite sAH/sAL (same-wave DS
        // ops retire in order; A-frags above were already read)
        #pragma unroll
        for (int mt = 0; mt < 2; ++mt)
            #pragma unroll
            for (int nt = 0; nt < 4; ++nt) {
                const int col = nt * 16 + ln;
                #pragma unroll
                for (int r = 0; r < 4; ++r) {
                    float v = fmaxf(acc2[mt][nt][r] + b2v[nt], 0.0f);
                    const unsigned short hb = bf16rn(v);
                    const unsigned short lb = bf16rn(v - bf16tof(hb));
                    const int rl = mt * 16 + q * 4 + r;
                    sAH[rl * 72 + col] = hb;
                    sAL[rl * 72 + col] = lb;
                }
            }

        // ---------------- layer 3 ----------------
        short8 a3h[2][2], a3l[2][2];
        #pragma unroll
        for (int mt = 0; mt < 2; ++mt)
            #pragma unroll
            for (int ks = 0; ks < 2; ++ks) {
                const int row = mt * 16 + ln;
                a3h[mt][ks] = ld8(&sAH[row * 72 + ks * 32 + q * 8]);
                a3l[mt][ks] = ld8(&sAL[row * 72 + ks * 32 + q * 8]);
            }
        f32x4 acc3[2] = {zero4, zero4};
        #pragma unroll
        for (int ks = 0; ks < 2; ++ks) {
            // W3 pre-padded to 16 rows (3..15 zero) -> no divergent mask
            const short8 bh = ld8(&wsw[W3H_OFF + ln * 64 + ks * 32 + q * 8]);
            const short8 bl = ld8(&wsw[W3L_OFF + ln * 64 + ks * 32 + q * 8]);
            #pragma unroll
            for (int mt = 0; mt < 2; ++mt) {
                f32x4 a = acc3[mt];
                a = MFMA(a3l[mt][ks], bh, a);
                a = MFMA(a3h[mt][ks], bl, a);
                a = MFMA(a3h[mt][ks], bh, a);
                acc3[mt] = a;
            }
        }
        // store: C col = ln (channel, <3), rows = samples
        if (ln < 3) {
            #pragma unroll
            for (int mt = 0; mt < 2; ++mt)
                #pragma unroll
                for (int r = 0; r < 4; ++r) {
                    const long sg = base + mh * 32 + mt * 16 + q * 4 + r;
                    if (sg < (long)n) out[sg * 3 + ln] = acc3[mt][r] + b3v;
                }
        }
    }
}

extern "C" void kernel_launch(void* const* d_in, const int* in_sizes, int n_in,
                              void* d_out, int out_size, void* d_ws, size_t ws_size,
                              hipStream_t stream) {
    const float* x      = (const float*)d_in[0];
    const float* tables = (const float*)d_in[1];
    const float* W1     = (const float*)d_in[2];
    const float* b1v    = (const float*)d_in[3];
    const float* W2     = (const float*)d_in[4];
    const float* b2v    = (const float*)d_in[5];
    const float* W3     = (const float*)d_in[6];
    const float* b3v    = (const float*)d_in[7];
    float* out = (float*)d_out;
    unsigned short* wsu = (unsigned short*)d_ws;

    const int n = in_sizes[0] / 2;   // B

    // Replicate numpy's RES computation on the host (glibc libm, float64).
    ResArr ra;
    const double bb = exp((log(512.0) - log(16.0)) / 15.0);
    for (int k = 0; k < 16; ++k) ra.r[k] = (float)floor(16.0 * pow(bb, (double)k));

    // Prepass: hi/lo bf16 weight split into workspace (stream-ordered).
    hipLaunchKernelGGL(split_weights, dim3(8), dim3(256), 0, stream, W1, W2, W3, wsu);

    dim3 grid((n + 63) / 64), block(64);
    hipLaunchKernelGGL(mh_mfma, grid, block, 0, stream,
                       x, tables, wsu, b1v, b2v, b3v, out, ra, n);
}